// Round 3
// baseline (1336.650 us; speedup 1.0000x reference)
//
#include <hip/hip_runtime.h>
#include <hip/hip_bf16.h>
#include <math.h>

// ---------------------------------------------------------------------------
// Swin block: LN1 -> shift+window QKV attn proj +res -> LN2 -> MLP +res
// B=32 H=W=56 C=384 NH=12 HD=32 WS=7 SS=3 N=49 NW=64 M=100352 MLP_H=1536
// Round 5: phase-interleaved GEMM at the PROVEN 128 KiB LDS budget.
//   Round-4 post-mortem: container failed twice, no counters. Prime suspect:
//   144 KiB static LDS (> any harness-verified size; m201 template = 128 KiB).
//   Schedule re-audited and kept; buffering made asymmetric to fit 128 KiB:
//     A: 3 buffers (96 KiB), depth-2 (HBM-cold stream, ~900cyc -> 4-phase
//        issue->consume cover). B: 2 buffers (32 KiB), depth-1 (weights are
//        L2/L3-hot, ~250cyc -> 2-phase cover suffices).
//   Per wave per K-tile: issue [B(t+1) x2, A(t+2) x4] in phase A; tile-final
//   s_waitcnt vmcnt(4) retires A(t+1)+B(t+1), keeps A(t+2) in flight
//   (in-order retirement ledger: [A(t+1)4, B(t+1)2, A(t+2)4]). vmcnt(0)
//   only at the tail. nkt in {6,24} -> unroll by 6, static buf indices.
// Workspace layout (bytes):
//   0         wt_qkv  (1152x384 bf16)
//   884736    wt_proj (384x384 bf16)
//   1179648   wt_fc1  (1536x384 bf16)
//   2359296   wt_fc2  (384x1536 bf16)
//   3538944   biasM   (12x49x49 f32)
//   3654656   xw      (100352x384 bf16)   } reused as hidden (100352x1536 bf16)
//   80724992  qkv     (100352x1152 bf16)  }
//   311936000 attn_out(100352x384 bf16)   reused as hn
// ---------------------------------------------------------------------------

typedef short bf16x8 __attribute__((ext_vector_type(8)));
typedef float f32x4 __attribute__((ext_vector_type(4)));

#define GLOAD_LDS16(g, s)                                                      \
    __builtin_amdgcn_global_load_lds(                                          \
        (const __attribute__((address_space(1))) void*)(g),                    \
        (__attribute__((address_space(3))) void*)(s), 16, 0, 0)

#define SBAR()                                                                 \
    {                                                                          \
        __builtin_amdgcn_s_barrier();                                          \
        __builtin_amdgcn_sched_barrier(0);                                     \
    }

// ---- merged prep: 4 weight transposes (f32->bf16) + rel-pos bias matrix ----
__global__ __launch_bounds__(256) void prep_k(
    const float* __restrict__ qkvw, const float* __restrict__ projw,
    const float* __restrict__ fc1w, const float* __restrict__ fc2w,
    const float* __restrict__ rpb,
    __hip_bfloat16* __restrict__ wt_qkv, __hip_bfloat16* __restrict__ wt_proj,
    __hip_bfloat16* __restrict__ wt_fc1, __hip_bfloat16* __restrict__ wt_fc2,
    float* __restrict__ biasM) {
    int id = blockIdx.x * 256 + threadIdx.x;
    if (id < 442368) {  // qkv_w (384x1152)
        int k = id / 1152, n = id % 1152;
        wt_qkv[(size_t)n * 384 + k] = __float2bfloat16(qkvw[id]);
        return;
    }
    id -= 442368;
    if (id < 147456) {  // proj_w (384x384)
        int k = id / 384, n = id % 384;
        wt_proj[(size_t)n * 384 + k] = __float2bfloat16(projw[id]);
        return;
    }
    id -= 147456;
    if (id < 589824) {  // fc1_w (384x1536)
        int k = id / 1536, n = id % 1536;
        wt_fc1[(size_t)n * 384 + k] = __float2bfloat16(fc1w[id]);
        return;
    }
    id -= 589824;
    if (id < 589824) {  // fc2_w (1536x384)
        int k = id / 384, n = id % 384;
        wt_fc2[(size_t)n * 1536 + k] = __float2bfloat16(fc2w[id]);
        return;
    }
    id -= 589824;
    if (id < 28812) {  // biasM[h][i][j]
        int h = id / 2401, rem = id % 2401, i = rem / 49, j = rem % 49;
        int ih = i / 7, iw = i % 7, jh = j / 7, jw = j % 7;
        int idx = (ih - jh + 6) * 13 + (iw - jw + 6);
        biasM[id] = rpb[idx * 12 + h];
    }
}

// ---- LayerNorm. MODE 0: gather shifted+window-partitioned rows -> xw -------
// ---- MODE 1: plain image rows (x_res -> hn) --------------------------------
template <int MODE>
__global__ __launch_bounds__(256) void ln_k(const float* __restrict__ X,
                                            const float* __restrict__ w,
                                            const float* __restrict__ b,
                                            __hip_bfloat16* __restrict__ out) {
    int wv = threadIdx.x >> 6, lane = threadIdx.x & 63;
    int row = blockIdx.x * 4 + wv;  // output row
    size_t src_row;
    if (MODE == 0) {
        int wi = row / 49, t = row % 49;
        int bb = wi >> 6, wrem = wi & 63;
        int wh = wrem >> 3, ww = wrem & 7;
        int th = t / 7, tw = t % 7;
        int hi = (wh * 7 + th + 3) % 56;      // roll(-3): shifted[hs]=x[(hs+3)%56]
        int wimg = (ww * 7 + tw + 3) % 56;
        src_row = (size_t)(bb * 3136 + hi * 56 + wimg);
    } else {
        src_row = row;
    }
    const float* src = X + src_row * 384;
    float v[6];
    float s = 0.f, sq = 0.f;
#pragma unroll
    for (int i = 0; i < 6; i++) {
        v[i] = src[lane + i * 64];
        s += v[i];
        sq += v[i] * v[i];
    }
#pragma unroll
    for (int m = 32; m >= 1; m >>= 1) {
        s += __shfl_xor(s, m, 64);
        sq += __shfl_xor(sq, m, 64);
    }
    float mean = s * (1.f / 384.f);
    float var = sq * (1.f / 384.f) - mean * mean;
    float rstd = rsqrtf(var + 1e-5f);
    size_t orow = (size_t)row * 384;
#pragma unroll
    for (int i = 0; i < 6; i++) {
        int c = lane + i * 64;
        out[orow + c] = __float2bfloat16((v[i] - mean) * rstd * w[c] + b[c]);
    }
}

// ---- 256x128x(BK=64) bf16 MFMA GEMM, A[M,K] x Bt[N,K]^T, 512 threads -------
// 8 waves as 4(M)x2(N); per-wave 64x64 out = 4x4 f32x4 acc.
// A: 3 LDS buffers (tile t -> buf t%3, depth-2). B: 2 buffers (t -> t&1,
// depth-1). Per K-tile two phases:
//   PA: ds_read B-all + A-rows i=0,1 (12xb128) | stage B(t+1) then A(t+2)
//       -> SBAR -> lgkmcnt(0) -> setprio(1) 16 MFMA setprio(0) -> SBAR
//   PB: ds_read A-rows i=2,3 (4xb128) -> SBAR -> lgkmcnt(0)
//       -> setprio(1) 16 MFMA setprio(0) -> [vmcnt(4|0) SBAR]
// vmcnt ledger at tile-t final wait (in-order, oldest first):
//   [A(t+1) x4 (issued t-1 PA), B(t+1) x2 (t PA), A(t+2) x4 (t PA)]
//   -> vmcnt(4) retires A(t+1)+B(t+1), leaves A(t+2) in flight.
// WAR: buf being staged was last ds_read one tile ago; those reads drained
// by lgkmcnt(0) before that tile's final barrier; stage issued after it.
// Swizzle: row r of a tile holds logical 16B-chunk q at physical slot
// q^(r&7); staging lane l pre-swizzles its global column by (l&7)^((l>>3)&7)
// so the gload_lds dest stays linear; ds_read applies the same XOR. 16 lanes
// of a quarter-wave then hit all 32 banks 2-way (free).
// EPI 0: +bias -> bf16 (qkv)        EPI 1: +bias, window-reverse+unshift,
// EPI 2: +bias, GELU -> bf16 (fc1)         +residual(x) -> f32 (proj)
// EPI 3: +bias +residual -> f32 (fc2)
template <int EPI>
__global__ __launch_bounds__(512, 1) void gemm_k(
    const __hip_bfloat16* __restrict__ A, const __hip_bfloat16* __restrict__ Bt,
    const float* __restrict__ bias, int K, int nTilesN,
    __hip_bfloat16* outb, float* outf, const float* resin) {
    __shared__ __align__(16) __hip_bfloat16 Asm[3][256 * 64];  // 96 KiB
    __shared__ __align__(16) __hip_bfloat16 Bsm[2][128 * 64];  // 32 KiB
    // chunked XCD swizzle (all grids %8==0): tN-siblings share one L2
    int bid = blockIdx.x;
    bid = (bid & 7) * ((int)gridDim.x >> 3) + (bid >> 3);
    int tM = bid / nTilesN, tN = bid % nTilesN;
    size_t m0 = (size_t)tM * 256;
    int n0 = tN * 128;
    int tid = threadIdx.x, wv = tid >> 6, lane = tid & 63;
    int wr = wv >> 1, wc = wv & 1;  // wave grid 4(M) x 2(N)
    int lm = lane & 15, lg = lane >> 4;

    f32x4 acc[4][4];
#pragma unroll
    for (int i = 0; i < 4; i++)
#pragma unroll
        for (int j = 0; j < 4; j++) acc[i][j] = (f32x4){0.f, 0.f, 0.f, 0.f};

    // staging source (swizzle pre-applied): lane l covers row l>>3 of its
    // chunk, physical slot l&7 <- logical chunk (l&7)^((l>>3)&7)
    int srow = lane >> 3;
    int sswz = ((lane & 7) ^ srow) * 8;
    const __hip_bfloat16* pA = A + (m0 + wv * 32 + srow) * K + sswz;
    const __hip_bfloat16* pB = Bt + (size_t)(n0 + wv * 16 + srow) * K + sswz;

    // ds_read offsets: af(i,kh) = aB[(wr*64+i*16+lm)*64 + ((kh*4+lg)^(lm&7))*8]
    int swz0 = ((0 + lg) ^ (lm & 7)) * 8;
    int swz1 = ((4 + lg) ^ (lm & 7)) * 8;
    int arow = (wr * 64 + lm) * 64;
    int brow = (wc * 64 + lm) * 64;

    int nkt = K >> 6;  // 6 (K=384) or 24 (K=1536); divisible by 6

#define STAGE_A(buf, c, k2) \
    GLOAD_LDS16(pA + (size_t)(c) * 8 * K + (k2), &Asm[buf][(wv * 4 + (c)) * 512])
#define STAGE_B(buf, c, k2) \
    GLOAD_LDS16(pB + (size_t)(c) * 8 * K + (k2), &Bsm[buf][(wv * 2 + (c)) * 512])

    // prologue: B(0), A(0), A(1). vmcnt(4) retires B(0)+A(0), A(1) in flight.
    STAGE_B(0, 0, 0); STAGE_B(0, 1, 0);
    STAGE_A(0, 0, 0); STAGE_A(0, 1, 0); STAGE_A(0, 2, 0); STAGE_A(0, 3, 0);
    STAGE_A(1, 0, 64); STAGE_A(1, 1, 64); STAGE_A(1, 2, 64); STAGE_A(1, 3, 64);
    asm volatile("s_waitcnt vmcnt(4)" ::: "memory");
    SBAR();

#define KTILE(CA, CB, T)                                                        \
    {                                                                           \
        constexpr int NA = ((CA) + 2) % 3;                                      \
        constexpr int NB = (CB) ^ 1;                                            \
        const __hip_bfloat16* aB = &Asm[CA][0];                                 \
        const __hip_bfloat16* bB = &Bsm[CB][0];                                 \
        const bool sta = (T) + 2 < nkt;                                         \
        const bool stb = (T) + 1 < nkt;                                         \
        const int k1 = ((T) + 1) << 6, k2 = ((T) + 2) << 6;                     \
        bf16x8 vbf[4][2], vaA[2], vaB_[2], vaC[2], vaD[2];                      \
        _Pragma("unroll") for (int j = 0; j < 4; j++) {                         \
            vbf[j][0] = *(const bf16x8*)&bB[brow + j * 1024 + swz0];            \
            vbf[j][1] = *(const bf16x8*)&bB[brow + j * 1024 + swz1];            \
        }                                                                       \
        vaA[0] = *(const bf16x8*)&aB[arow + swz0];                              \
        vaA[1] = *(const bf16x8*)&aB[arow + swz1];                              \
        vaB_[0] = *(const bf16x8*)&aB[arow + 1024 + swz0];                      \
        vaB_[1] = *(const bf16x8*)&aB[arow + 1024 + swz1];                      \
        if (stb) { STAGE_B(NB, 0, k1); STAGE_B(NB, 1, k1); }                    \
        if (sta) {                                                              \
            STAGE_A(NA, 0, k2); STAGE_A(NA, 1, k2);                             \
            STAGE_A(NA, 2, k2); STAGE_A(NA, 3, k2);                             \
        }                                                                       \
        SBAR();                                                                 \
        asm volatile("s_waitcnt lgkmcnt(0)" ::: "memory");                      \
        __builtin_amdgcn_sched_barrier(0);                                      \
        __builtin_amdgcn_s_setprio(1);                                          \
        _Pragma("unroll") for (int kh = 0; kh < 2; kh++)                        \
            _Pragma("unroll") for (int j = 0; j < 4; j++) {                     \
                acc[0][j] = __builtin_amdgcn_mfma_f32_16x16x32_bf16(            \
                    vaA[kh], vbf[j][kh], acc[0][j], 0, 0, 0);                   \
                acc[1][j] = __builtin_amdgcn_mfma_f32_16x16x32_bf16(            \
                    vaB_[kh], vbf[j][kh], acc[1][j], 0, 0, 0);                  \
            }                                                                   \
        __builtin_amdgcn_s_setprio(0);                                          \
        SBAR();                                                                 \
        vaC[0] = *(const bf16x8*)&aB[arow + 2048 + swz0];                       \
        vaC[1] = *(const bf16x8*)&aB[arow + 2048 + swz1];                       \
        vaD[0] = *(const bf16x8*)&aB[arow + 3072 + swz0];                       \
        vaD[1] = *(const bf16x8*)&aB[arow + 3072 + swz1];                       \
        SBAR();                                                                 \
        asm volatile("s_waitcnt lgkmcnt(0)" ::: "memory");                      \
        __builtin_amdgcn_sched_barrier(0);                                      \
        __builtin_amdgcn_s_setprio(1);                                          \
        _Pragma("unroll") for (int kh = 0; kh < 2; kh++)                        \
            _Pragma("unroll") for (int j = 0; j < 4; j++) {                     \
                acc[2][j] = __builtin_amdgcn_mfma_f32_16x16x32_bf16(            \
                    vaC[kh], vbf[j][kh], acc[2][j], 0, 0, 0);                   \
                acc[3][j] = __builtin_amdgcn_mfma_f32_16x16x32_bf16(            \
                    vaD[kh], vbf[j][kh], acc[3][j], 0, 0, 0);                   \
            }                                                                   \
        __builtin_amdgcn_s_setprio(0);                                          \
        if (stb) {                                                              \
            if (sta) asm volatile("s_waitcnt vmcnt(4)" ::: "memory");           \
            else     asm volatile("s_waitcnt vmcnt(0)" ::: "memory");           \
            SBAR();                                                             \
        }                                                                       \
    }

    for (int kt = 0; kt < nkt; kt += 6) {
        KTILE(0, 0, kt)
        KTILE(1, 1, kt + 1)
        KTILE(2, 0, kt + 2)
        KTILE(0, 1, kt + 3)
        KTILE(1, 0, kt + 4)
        KTILE(2, 1, kt + 5)
    }
#undef KTILE
#undef STAGE_A
#undef STAGE_B

    int ld = nTilesN * 128;
#pragma unroll
    for (int i = 0; i < 4; i++) {
#pragma unroll
        for (int r = 0; r < 4; r++) {
            int row = (int)m0 + wr * 64 + i * 16 + lg * 4 + r;
#pragma unroll
            for (int j = 0; j < 4; j++) {
                int col = n0 + wc * 64 + j * 16 + lm;
                float val = acc[i][j][r] + bias[col];
                if (EPI == 0) {
                    outb[(size_t)row * ld + col] = __float2bfloat16(val);
                } else if (EPI == 2) {
                    float g = 0.5f * val * (1.f + erff(val * 0.70710678118f));
                    outb[(size_t)row * ld + col] = __float2bfloat16(g);
                } else if (EPI == 1) {
                    // window-reverse + unshift + residual: row -> image pos
                    int wi = row / 49, t = row % 49;
                    int bb = wi >> 6, wrem = wi & 63;
                    int wh = wrem >> 3, ww = wrem & 7;
                    int th = t / 7, tw = t % 7;
                    int hi = (wh * 7 + th + 3) % 56;
                    int wimg = (ww * 7 + tw + 3) % 56;
                    size_t pos = (size_t)(bb * 3136 + hi * 56 + wimg) * 384 + col;
                    outf[pos] = resin[pos] + val;
                } else {  // EPI 3
                    size_t pos = (size_t)row * 384 + col;
                    outf[pos] = resin[pos] + val;
                }
            }
        }
    }
}

// ---- windowed attention: one block per (window, head) ----------------------
// LDS rows padded to 72 elems (144 B) -> 2-way bank access (free).
__global__ __launch_bounds__(256) void attn_k(const __hip_bfloat16* __restrict__ qkv,
                                              const float* __restrict__ biasM,
                                              __hip_bfloat16* __restrict__ out) {
    __shared__ __align__(16) __hip_bfloat16 vt[32 * 72];  // [dim][token(+pad)]
    __shared__ __align__(16) __hip_bfloat16 P[64 * 72];   // softmax probs
    // chunked XCD swizzle: 12 heads of a window share its qkv rows in L2
    int bid = blockIdx.x;
    bid = (bid & 7) * ((int)gridDim.x >> 3) + (bid >> 3);
    int wi = bid / 12, h = bid % 12;
    int tid = threadIdx.x, wv = tid >> 6, lane = tid & 63;
    int lm = lane & 15, lg = lane >> 4;
    int wrem = wi & 63, wh = wrem >> 3, ww = wrem & 7;

    // zero vt (covers token pad 49..71)
#pragma unroll
    for (int i = 0; i < 9; i++) vt[tid * 9 + i] = __float2bfloat16(0.f);
    __syncthreads();
    // stage v transposed: vt[d][t] = v[t][d]
    if (tid < 196) {
        int t = tid >> 2, d0 = (tid & 3) * 8;
        bf16x8 vv = *(const bf16x8*)(qkv + (size_t)(wi * 49 + t) * 1152 + 768 + h * 32 + d0);
#pragma unroll
        for (int i = 0; i < 8; i++) vt[(d0 + i) * 72 + t] = ((__hip_bfloat16*)&vv)[i];
    }

    // S = q @ k^T  (wave wv owns row-tile wv; frags straight from global)
    int qrow = wv * 16 + lm;
    if (qrow > 48) qrow = 48;
    bf16x8 aq = *(const bf16x8*)(qkv + (size_t)(wi * 49 + qrow) * 1152 + h * 32 + lg * 8);
    f32x4 S[4];
#pragma unroll
    for (int ct = 0; ct < 4; ct++) {
        int krow = ct * 16 + lm;
        if (krow > 48) krow = 48;
        bf16x8 bk = *(const bf16x8*)(qkv + (size_t)(wi * 49 + krow) * 1152 + 384 + h * 32 + lg * 8);
        S[ct] = __builtin_amdgcn_mfma_f32_16x16x32_bf16(aq, bk, (f32x4){0.f, 0.f, 0.f, 0.f}, 0, 0, 0);
    }

    // scale + rel-pos bias + shift mask + row softmax -> P (bf16, LDS)
    const float scale = 0.17677669529663687f;  // 32^-0.5
#pragma unroll
    for (int r = 0; r < 4; r++) {
        int irow = wv * 16 + lg * 4 + r;
        int ic = irow <= 48 ? irow : 48;
        int ith = ic / 7, itw = ic % 7;
        int ihs = wh * 7 + ith, iws = ww * 7 + itw;
        int ridi = (ihs < 49 ? 0 : (ihs < 53 ? 1 : 2)) * 3 + (iws < 49 ? 0 : (iws < 53 ? 1 : 2));
        float vals[4];
        float mx = -1e30f;
#pragma unroll
        for (int ct = 0; ct < 4; ct++) {
            int jcol = ct * 16 + lm;
            float sv;
            if (jcol < 49) {
                int jth = jcol / 7, jtw = jcol % 7;
                int jhs = wh * 7 + jth, jws = ww * 7 + jtw;
                int ridj = (jhs < 49 ? 0 : (jhs < 53 ? 1 : 2)) * 3 + (jws < 49 ? 0 : (jws < 53 ? 1 : 2));
                sv = S[ct][r] * scale + biasM[h * 2401 + ic * 49 + jcol] +
                     (ridi != ridj ? -100.f : 0.f);
            } else {
                sv = -1e30f;  // pad cols -> prob 0
            }
            vals[ct] = sv;
            mx = fmaxf(mx, sv);
        }
#pragma unroll
        for (int m = 8; m >= 1; m >>= 1) mx = fmaxf(mx, __shfl_xor(mx, m, 64));
        float sum = 0.f;
#pragma unroll
        for (int ct = 0; ct < 4; ct++) {
            vals[ct] = __expf(vals[ct] - mx);
            sum += vals[ct];
        }
#pragma unroll
        for (int m = 8; m >= 1; m >>= 1) sum += __shfl_xor(sum, m, 64);
        float inv = 1.f / sum;
#pragma unroll
        for (int ct = 0; ct < 4; ct++)
            P[irow * 72 + ct * 16 + lm] = __float2bfloat16(vals[ct] * inv);
    }
    __syncthreads();

    // O = P @ v   (K=64 = two 32-steps; N=32 = two col-tiles)
    f32x4 O[2] = {{0.f, 0.f, 0.f, 0.f}, {0.f, 0.f, 0.f, 0.f}};
#pragma unroll
    for (int ks = 0; ks < 2; ks++) {
        bf16x8 ap = *(const bf16x8*)&P[(wv * 16 + lm) * 72 + ks * 32 + lg * 8];
#pragma unroll
        for (int nt = 0; nt < 2; nt++) {
            bf16x8 bv = *(const bf16x8*)&vt[(nt * 16 + lm) * 72 + ks * 32 + lg * 8];
            O[nt] = __builtin_amdgcn_mfma_f32_16x16x32_bf16(ap, bv, O[nt], 0, 0, 0);
        }
    }
#pragma unroll
    for (int r = 0; r < 4; r++) {
        int row = wv * 16 + lg * 4 + r;
        if (row < 49) {
            size_t base = (size_t)(wi * 49 + row) * 384 + h * 32;
            out[base + lm] = __float2bfloat16(O[0][r]);
            out[base + 16 + lm] = __float2bfloat16(O[1][r]);
        }
    }
}

extern "C" void kernel_launch(void* const* d_in, const int* in_sizes, int n_in,
                              void* d_out, int out_size, void* d_ws, size_t ws_size,
                              hipStream_t stream) {
    (void)in_sizes; (void)n_in; (void)out_size; (void)ws_size;
    const float* x     = (const float*)d_in[0];
    const float* n1w   = (const float*)d_in[1];
    const float* n1b   = (const float*)d_in[2];
    const float* qkvw  = (const float*)d_in[3];
    const float* qkvb  = (const float*)d_in[4];
    const float* rpb   = (const float*)d_in[5];
    const float* projw = (const float*)d_in[6];
    const float* projb = (const float*)d_in[7];
    const float* n2w   = (const float*)d_in[8];
    const float* n2b   = (const float*)d_in[9];
    const float* fc1w  = (const float*)d_in[10];
    const float* fc1b  = (const float*)d_in[11];
    const float* fc2w  = (const float*)d_in[12];
    const float* fc2b  = (const float*)d_in[13];
    float* out = (float*)d_out;

    char* ws = (char*)d_ws;
    __hip_bfloat16* wt_qkv  = (__hip_bfloat16*)(ws + 0);
    __hip_bfloat16* wt_proj = (__hip_bfloat16*)(ws + 884736);
    __hip_bfloat16* wt_fc1  = (__hip_bfloat16*)(ws + 1179648);
    __hip_bfloat16* wt_fc2  = (__hip_bfloat16*)(ws + 2359296);
    float*          biasM   = (float*)(ws + 3538944);
    __hip_bfloat16* xw      = (__hip_bfloat16*)(ws + 3654656);
    __hip_bfloat16* qkv     = (__hip_bfloat16*)(ws + 80724992);
    __hip_bfloat16* attn_o  = (__hip_bfloat16*)(ws + 311936000);
    __hip_bfloat16* hidden  = xw;      // reuse xw+qkv region (308 MB)
    __hip_bfloat16* hn      = attn_o;  // reuse attn_out region

    // merged weight-convert + bias-matrix prep (1,798,284 elements)
    prep_k<<<7025, 256, 0, stream>>>(qkvw, projw, fc1w, fc2w, rpb,
                                     wt_qkv, wt_proj, wt_fc1, wt_fc2, biasM);

    // LN1 + cyclic shift + window partition
    ln_k<0><<<25088, 256, 0, stream>>>(x, n1w, n1b, xw);
    // QKV projection (grid 3528 % 8 == 0)
    gemm_k<0><<<392 * 9, 512, 0, stream>>>(xw, wt_qkv, qkvb, 384, 9, qkv, nullptr, nullptr);
    // windowed attention (grid 24576 % 8 == 0)
    attn_k<<<2048 * 12, 256, 0, stream>>>(qkv, biasM, attn_o);
    // proj + window reverse + unshift + residual -> x_res (in d_out, fp32)
    gemm_k<1><<<392 * 3, 512, 0, stream>>>(attn_o, wt_proj, projb, 384, 3, nullptr, out, x);
    // LN2
    ln_k<1><<<25088, 256, 0, stream>>>(out, n2w, n2b, hn);
    // fc1 + GELU
    gemm_k<2><<<392 * 12, 512, 0, stream>>>(hn, wt_fc1, fc1b, 384, 12, hidden, nullptr, nullptr);
    // fc2 + residual -> d_out
    gemm_k<3><<<392 * 3, 512, 0, stream>>>(hidden, wt_fc2, fc2b, 1536, 3, nullptr, out, out);
}

// Round 4
// 1308.562 us; speedup vs baseline: 1.0215x; 1.0215x over previous
//
#include <hip/hip_runtime.h>
#include <hip/hip_bf16.h>
#include <math.h>

// ---------------------------------------------------------------------------
// Swin block: LN1 -> shift+window QKV attn proj +res -> LN2 -> MLP +res
// B=32 H=W=56 C=384 NH=12 HD=32 WS=7 SS=3 N=49 NW=64 M=100352 MLP_H=1536
// Round 6: GEMM rebuilt WITHOUT LDS-DMA in the K-loop.
//   Rounds 0/1/3 post-mortem: three different global_load_lds schedules all
//   pin at ~307us / 15.7% MfmaUtil -> the compiler's conservative vmcnt(0)
//   before ds_reads (LDS-DMA dependency) serializes every schedule. Fix by
//   construction: A-fragments go global->VGPR directly (tall-skinny GEMM:
//   A has no intra-block reuse; VGPR loads get precise compiler vmcnt,
//   issued ~1.5 iters ahead). B is register-staged (global->VGPR->ds_write)
//   into a 2x16KB double buffer; the loop's single barrier needs only
//   lgkmcnt(0) -- NO vmcnt drain anywhere in the loop.
//   256 thr / 4 waves x (32 rows x 128 cols), BM=128 BN=128 BK=64,
//   acc 2x8 frags (64 VGPR), ds_write-side XOR swizzle (chunk ^= row&7).
//   ~2 blocks/CU so barrier stalls of one block hide under the other.
// Workspace layout (bytes):
//   0         wt_qkv  (1152x384 bf16)
//   884736    wt_proj (384x384 bf16)
//   1179648   wt_fc1  (1536x384 bf16)
//   2359296   wt_fc2  (384x1536 bf16)
//   3538944   biasM   (12x49x49 f32)
//   3654656   xw      (100352x384 bf16)   } reused as hidden (100352x1536 bf16)
//   80724992  qkv     (100352x1152 bf16)  }
//   311936000 attn_out(100352x384 bf16)   reused as hn
// ---------------------------------------------------------------------------

typedef short bf16x8 __attribute__((ext_vector_type(8)));
typedef float f32x4 __attribute__((ext_vector_type(4)));

// ---- merged prep: 4 weight transposes (f32->bf16) + rel-pos bias matrix ----
__global__ __launch_bounds__(256) void prep_k(
    const float* __restrict__ qkvw, const float* __restrict__ projw,
    const float* __restrict__ fc1w, const float* __restrict__ fc2w,
    const float* __restrict__ rpb,
    __hip_bfloat16* __restrict__ wt_qkv, __hip_bfloat16* __restrict__ wt_proj,
    __hip_bfloat16* __restrict__ wt_fc1, __hip_bfloat16* __restrict__ wt_fc2,
    float* __restrict__ biasM) {
    int id = blockIdx.x * 256 + threadIdx.x;
    if (id < 442368) {  // qkv_w (384x1152)
        int k = id / 1152, n = id % 1152;
        wt_qkv[(size_t)n * 384 + k] = __float2bfloat16(qkvw[id]);
        return;
    }
    id -= 442368;
    if (id < 147456) {  // proj_w (384x384)
        int k = id / 384, n = id % 384;
        wt_proj[(size_t)n * 384 + k] = __float2bfloat16(projw[id]);
        return;
    }
    id -= 147456;
    if (id < 589824) {  // fc1_w (384x1536)
        int k = id / 1536, n = id % 1536;
        wt_fc1[(size_t)n * 384 + k] = __float2bfloat16(fc1w[id]);
        return;
    }
    id -= 589824;
    if (id < 589824) {  // fc2_w (1536x384)
        int k = id / 384, n = id % 384;
        wt_fc2[(size_t)n * 1536 + k] = __float2bfloat16(fc2w[id]);
        return;
    }
    id -= 589824;
    if (id < 28812) {  // biasM[h][i][j]
        int h = id / 2401, rem = id % 2401, i = rem / 49, j = rem % 49;
        int ih = i / 7, iw = i % 7, jh = j / 7, jw = j % 7;
        int idx = (ih - jh + 6) * 13 + (iw - jw + 6);
        biasM[id] = rpb[idx * 12 + h];
    }
}

// ---- LayerNorm. MODE 0: gather shifted+window-partitioned rows -> xw -------
// ---- MODE 1: plain image rows (x_res -> hn) --------------------------------
template <int MODE>
__global__ __launch_bounds__(256) void ln_k(const float* __restrict__ X,
                                            const float* __restrict__ w,
                                            const float* __restrict__ b,
                                            __hip_bfloat16* __restrict__ out) {
    int wv = threadIdx.x >> 6, lane = threadIdx.x & 63;
    int row = blockIdx.x * 4 + wv;  // output row
    size_t src_row;
    if (MODE == 0) {
        int wi = row / 49, t = row % 49;
        int bb = wi >> 6, wrem = wi & 63;
        int wh = wrem >> 3, ww = wrem & 7;
        int th = t / 7, tw = t % 7;
        int hi = (wh * 7 + th + 3) % 56;      // roll(-3): shifted[hs]=x[(hs+3)%56]
        int wimg = (ww * 7 + tw + 3) % 56;
        src_row = (size_t)(bb * 3136 + hi * 56 + wimg);
    } else {
        src_row = row;
    }
    const float* src = X + src_row * 384;
    float v[6];
    float s = 0.f, sq = 0.f;
#pragma unroll
    for (int i = 0; i < 6; i++) {
        v[i] = src[lane + i * 64];
        s += v[i];
        sq += v[i] * v[i];
    }
#pragma unroll
    for (int m = 32; m >= 1; m >>= 1) {
        s += __shfl_xor(s, m, 64);
        sq += __shfl_xor(sq, m, 64);
    }
    float mean = s * (1.f / 384.f);
    float var = sq * (1.f / 384.f) - mean * mean;
    float rstd = rsqrtf(var + 1e-5f);
    size_t orow = (size_t)row * 384;
#pragma unroll
    for (int i = 0; i < 6; i++) {
        int c = lane + i * 64;
        out[orow + c] = __float2bfloat16((v[i] - mean) * rstd * w[c] + b[c]);
    }
}

// ---- 128x128x(BK=64) bf16 MFMA GEMM, A[M,K] x Bt[N,K]^T, 256 threads -------
// 4 waves, each owning 32 rows x 128 cols (acc[2][8] f32x4 = 64 VGPR).
// A: global->VGPR fragments only (no LDS). Per iter, A(t+2) loads issue
//    AFTER the MFMAs that consume the same register set (WAR) -> in flight
//    ~1.7 iterations; compiler inserts precise vmcnt waits at first use.
// B: register-staged double-buffered LDS. Iter t: ds_write B(t+1) (regs
//    loaded at t-1) -> issue global B(t+2) -> ds_read frags of t + 32 MFMA
//    -> issue A(t+2) -> lgkmcnt(0) -> s_barrier. No vmcnt drain in loop.
// LDS swizzle: row r stores logical 16B-chunk c at slot c^(r&7); ds_write
// applies it directly (we own the writes), ds_read XORs with lm&7.
// EPI 0: +bias -> bf16 (qkv)        EPI 1: +bias, window-reverse+unshift,
// EPI 2: +bias, GELU -> bf16 (fc1)         +residual(x) -> f32 (proj)
// EPI 3: +bias +residual -> f32 (fc2)
template <int EPI>
__global__ __launch_bounds__(256, 2) void gemm_k(
    const __hip_bfloat16* __restrict__ A, const __hip_bfloat16* __restrict__ Bt,
    const float* __restrict__ bias, int K, int nTilesN,
    __hip_bfloat16* outb, float* outf, const float* resin) {
    __shared__ __align__(16) __hip_bfloat16 lb[2][128 * 64];  // 32 KiB
    // chunked XCD swizzle (all grids %8==0): tN-siblings share one L2
    int bid = blockIdx.x;
    bid = (bid & 7) * ((int)gridDim.x >> 3) + (bid >> 3);
    int tM = bid / nTilesN, tN = bid % nTilesN;
    size_t m0 = (size_t)tM * 128;
    int n0 = tN * 128;
    int tid = threadIdx.x, wv = tid >> 6, lane = tid & 63;
    int lm = lane & 15, lg = lane >> 4;

    f32x4 acc[2][8];
#pragma unroll
    for (int m = 0; m < 2; m++)
#pragma unroll
        for (int j = 0; j < 8; j++) acc[m][j] = (f32x4){0.f, 0.f, 0.f, 0.f};

    // A-fragment base: a[m][kh] <- 16B at A[(m0+wv*32+m*16+lm)*K + t*64+kh*32+lg*8]
    const __hip_bfloat16* pA = A + (m0 + wv * 32 + lm) * K + lg * 8;
    // B-staging source: thread covers 64B of row brow at col (tid&1)*32
    int brow = tid >> 1;
    const __hip_bfloat16* pB = Bt + (size_t)(n0 + brow) * K + (tid & 1) * 32;
    // ds_write element offsets (swizzled); kc = (tid&1)*4 + i
    int wof[4];
#pragma unroll
    for (int i = 0; i < 4; i++)
        wof[i] = brow * 64 + ((((tid & 1) * 4 + i) ^ (brow & 7)) * 8);
    // ds_read swizzled chunk offsets for kh=0,1
    int rof0 = ((0 + lg) ^ (lm & 7)) * 8;
    int rof1 = ((4 + lg) ^ (lm & 7)) * 8;

    int nkt = K >> 6;  // 6 (K=384) or 24 (K=1536) -- always even

    bf16x8 bst[4];   // B staging regs (one tile's 64B slice per thread)
    bf16x8 aA[2][2], aB[2][2];  // A fragment sets, alternating tiles

#define LOADB(T)                                                               \
    do {                                                                       \
        const __hip_bfloat16* p_ = pB + (size_t)(T) * 64;                      \
        bst[0] = *(const bf16x8*)(p_);                                         \
        bst[1] = *(const bf16x8*)(p_ + 8);                                     \
        bst[2] = *(const bf16x8*)(p_ + 16);                                    \
        bst[3] = *(const bf16x8*)(p_ + 24);                                    \
    } while (0)
#define LOADA(DST, T)                                                          \
    do {                                                                       \
        const __hip_bfloat16* p_ = pA + (size_t)(T) * 64;                      \
        DST[0][0] = *(const bf16x8*)(p_);                                      \
        DST[0][1] = *(const bf16x8*)(p_ + 32);                                 \
        DST[1][0] = *(const bf16x8*)(p_ + (size_t)16 * K);                     \
        DST[1][1] = *(const bf16x8*)(p_ + (size_t)16 * K + 32);                \
    } while (0)
#define WRITEB(P)                                                              \
    do {                                                                       \
        *(bf16x8*)&lb[P][wof[0]] = bst[0];                                     \
        *(bf16x8*)&lb[P][wof[1]] = bst[1];                                     \
        *(bf16x8*)&lb[P][wof[2]] = bst[2];                                     \
        *(bf16x8*)&lb[P][wof[3]] = bst[3];                                     \
    } while (0)
#define COMPUTE(P, AC)                                                         \
    do {                                                                       \
        _Pragma("unroll") for (int j = 0; j < 8; j++) {                        \
            bf16x8 b0 = *(const bf16x8*)&lb[P][(j * 16 + lm) * 64 + rof0];     \
            bf16x8 b1 = *(const bf16x8*)&lb[P][(j * 16 + lm) * 64 + rof1];     \
            acc[0][j] = __builtin_amdgcn_mfma_f32_16x16x32_bf16(               \
                AC[0][0], b0, acc[0][j], 0, 0, 0);                             \
            acc[0][j] = __builtin_amdgcn_mfma_f32_16x16x32_bf16(               \
                AC[0][1], b1, acc[0][j], 0, 0, 0);                             \
            acc[1][j] = __builtin_amdgcn_mfma_f32_16x16x32_bf16(               \
                AC[1][0], b0, acc[1][j], 0, 0, 0);                             \
            acc[1][j] = __builtin_amdgcn_mfma_f32_16x16x32_bf16(               \
                AC[1][1], b1, acc[1][j], 0, 0, 0);                             \
        }                                                                      \
    } while (0)
#define ENDBAR()                                                               \
    do {                                                                       \
        asm volatile("s_waitcnt lgkmcnt(0)" ::: "memory");                     \
        __builtin_amdgcn_sched_barrier(0);                                     \
        __builtin_amdgcn_s_barrier();                                          \
        __builtin_amdgcn_sched_barrier(0);                                     \
    } while (0)
    // iter T (parity P): publish B(T+1), prefetch B(T+2)/A(T+2), compute T
#define ITER(P, AC, T)                                                         \
    do {                                                                       \
        if ((T) + 1 < nkt) WRITEB(P ^ 1);                                      \
        if ((T) + 2 < nkt) LOADB((T) + 2);                                     \
        COMPUTE(P, AC);                                                        \
        if ((T) + 2 < nkt) LOADA(AC, (T) + 2);                                 \
        ENDBAR();                                                              \
    } while (0)

    // prologue: B(0)->lb[0]; B(1),A(0),A(1) in regs/flight
    LOADB(0);
    LOADA(aA, 0);
    WRITEB(0);  // compiler waits vmcnt for bst precisely
    LOADB(1);
    LOADA(aB, 1);
    ENDBAR();

    for (int t = 0; t < nkt; t += 2) {
        ITER(0, aA, t);
        ITER(1, aB, t + 1);
    }
#undef ITER
#undef ENDBAR
#undef COMPUTE
#undef WRITEB
#undef LOADA
#undef LOADB

    int ld = nTilesN * 128;
#pragma unroll
    for (int m = 0; m < 2; m++) {
#pragma unroll
        for (int r = 0; r < 4; r++) {
            int row = (int)m0 + wv * 32 + m * 16 + lg * 4 + r;
#pragma unroll
            for (int j = 0; j < 8; j++) {
                int col = n0 + j * 16 + lm;
                float val = acc[m][j][r] + bias[col];
                if (EPI == 0) {
                    outb[(size_t)row * ld + col] = __float2bfloat16(val);
                } else if (EPI == 2) {
                    float g = 0.5f * val * (1.f + erff(val * 0.70710678118f));
                    outb[(size_t)row * ld + col] = __float2bfloat16(g);
                } else if (EPI == 1) {
                    // window-reverse + unshift + residual: row -> image pos
                    int wi = row / 49, t = row % 49;
                    int bb = wi >> 6, wrem = wi & 63;
                    int wh = wrem >> 3, ww = wrem & 7;
                    int th = t / 7, tw = t % 7;
                    int hi = (wh * 7 + th + 3) % 56;
                    int wimg = (ww * 7 + tw + 3) % 56;
                    size_t pos = (size_t)(bb * 3136 + hi * 56 + wimg) * 384 + col;
                    outf[pos] = resin[pos] + val;
                } else {  // EPI 3
                    size_t pos = (size_t)row * 384 + col;
                    outf[pos] = resin[pos] + val;
                }
            }
        }
    }
}

// ---- windowed attention: one block per (window, head) ----------------------
// LDS rows padded to 72 elems (144 B) -> 2-way bank access (free).
__global__ __launch_bounds__(256) void attn_k(const __hip_bfloat16* __restrict__ qkv,
                                              const float* __restrict__ biasM,
                                              __hip_bfloat16* __restrict__ out) {
    __shared__ __align__(16) __hip_bfloat16 vt[32 * 72];  // [dim][token(+pad)]
    __shared__ __align__(16) __hip_bfloat16 P[64 * 72];   // softmax probs
    // chunked XCD swizzle: 12 heads of a window share its qkv rows in L2
    int bid = blockIdx.x;
    bid = (bid & 7) * ((int)gridDim.x >> 3) + (bid >> 3);
    int wi = bid / 12, h = bid % 12;
    int tid = threadIdx.x, wv = tid >> 6, lane = tid & 63;
    int lm = lane & 15, lg = lane >> 4;
    int wrem = wi & 63, wh = wrem >> 3, ww = wrem & 7;

    // zero vt (covers token pad 49..71)
#pragma unroll
    for (int i = 0; i < 9; i++) vt[tid * 9 + i] = __float2bfloat16(0.f);
    __syncthreads();
    // stage v transposed: vt[d][t] = v[t][d]
    if (tid < 196) {
        int t = tid >> 2, d0 = (tid & 3) * 8;
        bf16x8 vv = *(const bf16x8*)(qkv + (size_t)(wi * 49 + t) * 1152 + 768 + h * 32 + d0);
#pragma unroll
        for (int i = 0; i < 8; i++) vt[(d0 + i) * 72 + t] = ((__hip_bfloat16*)&vv)[i];
    }

    // S = q @ k^T  (wave wv owns row-tile wv; frags straight from global)
    int qrow = wv * 16 + lm;
    if (qrow > 48) qrow = 48;
    bf16x8 aq = *(const bf16x8*)(qkv + (size_t)(wi * 49 + qrow) * 1152 + h * 32 + lg * 8);
    f32x4 S[4];
#pragma unroll
    for (int ct = 0; ct < 4; ct++) {
        int krow = ct * 16 + lm;
        if (krow > 48) krow = 48;
        bf16x8 bk = *(const bf16x8*)(qkv + (size_t)(wi * 49 + krow) * 1152 + 384 + h * 32 + lg * 8);
        S[ct] = __builtin_amdgcn_mfma_f32_16x16x32_bf16(aq, bk, (f32x4){0.f, 0.f, 0.f, 0.f}, 0, 0, 0);
    }

    // scale + rel-pos bias + shift mask + row softmax -> P (bf16, LDS)
    const float scale = 0.17677669529663687f;  // 32^-0.5
#pragma unroll
    for (int r = 0; r < 4; r++) {
        int irow = wv * 16 + lg * 4 + r;
        int ic = irow <= 48 ? irow : 48;
        int ith = ic / 7, itw = ic % 7;
        int ihs = wh * 7 + ith, iws = ww * 7 + itw;
        int ridi = (ihs < 49 ? 0 : (ihs < 53 ? 1 : 2)) * 3 + (iws < 49 ? 0 : (iws < 53 ? 1 : 2));
        float vals[4];
        float mx = -1e30f;
#pragma unroll
        for (int ct = 0; ct < 4; ct++) {
            int jcol = ct * 16 + lm;
            float sv;
            if (jcol < 49) {
                int jth = jcol / 7, jtw = jcol % 7;
                int jhs = wh * 7 + jth, jws = ww * 7 + jtw;
                int ridj = (jhs < 49 ? 0 : (jhs < 53 ? 1 : 2)) * 3 + (jws < 49 ? 0 : (jws < 53 ? 1 : 2));
                sv = S[ct][r] * scale + biasM[h * 2401 + ic * 49 + jcol] +
                     (ridi != ridj ? -100.f : 0.f);
            } else {
                sv = -1e30f;  // pad cols -> prob 0
            }
            vals[ct] = sv;
            mx = fmaxf(mx, sv);
        }
#pragma unroll
        for (int m = 8; m >= 1; m >>= 1) mx = fmaxf(mx, __shfl_xor(mx, m, 64));
        float sum = 0.f;
#pragma unroll
        for (int ct = 0; ct < 4; ct++) {
            vals[ct] = __expf(vals[ct] - mx);
            sum += vals[ct];
        }
#pragma unroll
        for (int m = 8; m >= 1; m >>= 1) sum += __shfl_xor(sum, m, 64);
        float inv = 1.f / sum;
#pragma unroll
        for (int ct = 0; ct < 4; ct++)
            P[irow * 72 + ct * 16 + lm] = __float2bfloat16(vals[ct] * inv);
    }
    __syncthreads();

    // O = P @ v   (K=64 = two 32-steps; N=32 = two col-tiles)
    f32x4 O[2] = {{0.f, 0.f, 0.f, 0.f}, {0.f, 0.f, 0.f, 0.f}};
#pragma unroll
    for (int ks = 0; ks < 2; ks++) {
        bf16x8 ap = *(const bf16x8*)&P[(wv * 16 + lm) * 72 + ks * 32 + lg * 8];
#pragma unroll
        for (int nt = 0; nt < 2; nt++) {
            bf16x8 bv = *(const bf16x8*)&vt[(nt * 16 + lm) * 72 + ks * 32 + lg * 8];
            O[nt] = __builtin_amdgcn_mfma_f32_16x16x32_bf16(ap, bv, O[nt], 0, 0, 0);
        }
    }
#pragma unroll
    for (int r = 0; r < 4; r++) {
        int row = wv * 16 + lg * 4 + r;
        if (row < 49) {
            size_t base = (size_t)(wi * 49 + row) * 384 + h * 32;
            out[base + lm] = __float2bfloat16(O[0][r]);
            out[base + 16 + lm] = __float2bfloat16(O[1][r]);
        }
    }
}

extern "C" void kernel_launch(void* const* d_in, const int* in_sizes, int n_in,
                              void* d_out, int out_size, void* d_ws, size_t ws_size,
                              hipStream_t stream) {
    (void)in_sizes; (void)n_in; (void)out_size; (void)ws_size;
    const float* x     = (const float*)d_in[0];
    const float* n1w   = (const float*)d_in[1];
    const float* n1b   = (const float*)d_in[2];
    const float* qkvw  = (const float*)d_in[3];
    const float* qkvb  = (const float*)d_in[4];
    const float* rpb   = (const float*)d_in[5];
    const float* projw = (const float*)d_in[6];
    const float* projb = (const float*)d_in[7];
    const float* n2w   = (const float*)d_in[8];
    const float* n2b   = (const float*)d_in[9];
    const float* fc1w  = (const float*)d_in[10];
    const float* fc1b  = (const float*)d_in[11];
    const float* fc2w  = (const float*)d_in[12];
    const float* fc2b  = (const float*)d_in[13];
    float* out = (float*)d_out;

    char* ws = (char*)d_ws;
    __hip_bfloat16* wt_qkv  = (__hip_bfloat16*)(ws + 0);
    __hip_bfloat16* wt_proj = (__hip_bfloat16*)(ws + 884736);
    __hip_bfloat16* wt_fc1  = (__hip_bfloat16*)(ws + 1179648);
    __hip_bfloat16* wt_fc2  = (__hip_bfloat16*)(ws + 2359296);
    float*          biasM   = (float*)(ws + 3538944);
    __hip_bfloat16* xw      = (__hip_bfloat16*)(ws + 3654656);
    __hip_bfloat16* qkv     = (__hip_bfloat16*)(ws + 80724992);
    __hip_bfloat16* attn_o  = (__hip_bfloat16*)(ws + 311936000);
    __hip_bfloat16* hidden  = xw;      // reuse xw+qkv region (308 MB)
    __hip_bfloat16* hn      = attn_o;  // reuse attn_out region

    // merged weight-convert + bias-matrix prep (1,798,284 elements)
    prep_k<<<7025, 256, 0, stream>>>(qkvw, projw, fc1w, fc2w, rpb,
                                     wt_qkv, wt_proj, wt_fc1, wt_fc2, biasM);

    // LN1 + cyclic shift + window partition
    ln_k<0><<<25088, 256, 0, stream>>>(x, n1w, n1b, xw);
    // QKV projection (grid 7056 % 8 == 0)
    gemm_k<0><<<784 * 9, 256, 0, stream>>>(xw, wt_qkv, qkvb, 384, 9, qkv, nullptr, nullptr);
    // windowed attention (grid 24576 % 8 == 0)
    attn_k<<<2048 * 12, 256, 0, stream>>>(qkv, biasM, attn_o);
    // proj + window reverse + unshift + residual -> x_res (in d_out, fp32)
    gemm_k<1><<<784 * 3, 256, 0, stream>>>(attn_o, wt_proj, projb, 384, 3, nullptr, out, x);
    // LN2
    ln_k<1><<<25088, 256, 0, stream>>>(out, n2w, n2b, hn);
    // fc1 + GELU
    gemm_k<2><<<784 * 12, 256, 0, stream>>>(hn, wt_fc1, fc1b, 384, 12, hidden, nullptr, nullptr);
    // fc2 + residual -> d_out
    gemm_k<3><<<784 * 3, 256, 0, stream>>>(hidden, wt_fc2, fc2b, 1536, 3, nullptr, out, out);
}

// Round 5
// 1204.304 us; speedup vs baseline: 1.1099x; 1.0866x over previous
//
#include <hip/hip_runtime.h>
#include <hip/hip_bf16.h>
#include <math.h>

// ---------------------------------------------------------------------------
// Swin block: LN1 -> shift+window QKV attn proj +res -> LN2 -> MLP +res
// B=32 H=W=56 C=384 NH=12 HD=32 WS=7 SS=3 N=49 NW=64 M=100352 MLP_H=1536
// Round 7: BYTES, not schedule. Rounds 0/1/3/4: four different K-loop
//   schedules all pin at ~308us; total vector-load bytes / 308us = 6.0 TB/s
//   = the streaming ceiling. The GEMMs are bytes-bound (L3-served loads
//   stream at HBM-like rate; FETCH_SIZE under-reports the binding traffic).
//   Fix: tile geometry. Load volume = A*(N/BN) + B*(M/BM).
//   BM=128 BN=384 BK=64, 1024 thr = 16 waves (4Mx4N), wave 32x96,
//   acc[2][6] f32x4 = 48 VGPR, launch_bounds(1024,4) -> <=128 VGPR,
//   16 waves/CU (occupancy 30%->50% rider). A+B reg-staged into one
//   128 KiB double buffer (proven budget), 4 chunks/thread/tile, XOR
//   swizzle both sides, round-4 parity skeleton (verified) unchanged.
//   GEMM bytes: 5.8 GB -> 4.0 GB (fc2 1.85->1.39, fc1 1.85->1.23,
//   qkv 1.39->0.92, proj 0.68->0.46).
// Workspace layout (bytes):
//   0         wt_qkv  (1152x384 bf16)
//   884736    wt_proj (384x384 bf16)
//   1179648   wt_fc1  (1536x384 bf16)
//   2359296   wt_fc2  (384x1536 bf16)
//   3538944   biasM   (12x49x49 f32)
//   3654656   xw      (100352x384 bf16)   } reused as hidden (100352x1536 bf16)
//   80724992  qkv     (100352x1152 bf16)  }
//   311936000 attn_out(100352x384 bf16)   reused as hn
// ---------------------------------------------------------------------------

typedef short bf16x8 __attribute__((ext_vector_type(8)));
typedef float f32x4 __attribute__((ext_vector_type(4)));

// ---- merged prep: 4 weight transposes (f32->bf16) + rel-pos bias matrix ----
__global__ __launch_bounds__(256) void prep_k(
    const float* __restrict__ qkvw, const float* __restrict__ projw,
    const float* __restrict__ fc1w, const float* __restrict__ fc2w,
    const float* __restrict__ rpb,
    __hip_bfloat16* __restrict__ wt_qkv, __hip_bfloat16* __restrict__ wt_proj,
    __hip_bfloat16* __restrict__ wt_fc1, __hip_bfloat16* __restrict__ wt_fc2,
    float* __restrict__ biasM) {
    int id = blockIdx.x * 256 + threadIdx.x;
    if (id < 442368) {  // qkv_w (384x1152)
        int k = id / 1152, n = id % 1152;
        wt_qkv[(size_t)n * 384 + k] = __float2bfloat16(qkvw[id]);
        return;
    }
    id -= 442368;
    if (id < 147456) {  // proj_w (384x384)
        int k = id / 384, n = id % 384;
        wt_proj[(size_t)n * 384 + k] = __float2bfloat16(projw[id]);
        return;
    }
    id -= 147456;
    if (id < 589824) {  // fc1_w (384x1536)
        int k = id / 1536, n = id % 1536;
        wt_fc1[(size_t)n * 384 + k] = __float2bfloat16(fc1w[id]);
        return;
    }
    id -= 589824;
    if (id < 589824) {  // fc2_w (1536x384)
        int k = id / 384, n = id % 384;
        wt_fc2[(size_t)n * 1536 + k] = __float2bfloat16(fc2w[id]);
        return;
    }
    id -= 589824;
    if (id < 28812) {  // biasM[h][i][j]
        int h = id / 2401, rem = id % 2401, i = rem / 49, j = rem % 49;
        int ih = i / 7, iw = i % 7, jh = j / 7, jw = j % 7;
        int idx = (ih - jh + 6) * 13 + (iw - jw + 6);
        biasM[id] = rpb[idx * 12 + h];
    }
}

// ---- LayerNorm. MODE 0: gather shifted+window-partitioned rows -> xw -------
// ---- MODE 1: plain image rows (x_res -> hn) --------------------------------
template <int MODE>
__global__ __launch_bounds__(256) void ln_k(const float* __restrict__ X,
                                            const float* __restrict__ w,
                                            const float* __restrict__ b,
                                            __hip_bfloat16* __restrict__ out) {
    int wv = threadIdx.x >> 6, lane = threadIdx.x & 63;
    int row = blockIdx.x * 4 + wv;  // output row
    size_t src_row;
    if (MODE == 0) {
        int wi = row / 49, t = row % 49;
        int bb = wi >> 6, wrem = wi & 63;
        int wh = wrem >> 3, ww = wrem & 7;
        int th = t / 7, tw = t % 7;
        int hi = (wh * 7 + th + 3) % 56;      // roll(-3): shifted[hs]=x[(hs+3)%56]
        int wimg = (ww * 7 + tw + 3) % 56;
        src_row = (size_t)(bb * 3136 + hi * 56 + wimg);
    } else {
        src_row = row;
    }
    const float* src = X + src_row * 384;
    float v[6];
    float s = 0.f, sq = 0.f;
#pragma unroll
    for (int i = 0; i < 6; i++) {
        v[i] = src[lane + i * 64];
        s += v[i];
        sq += v[i] * v[i];
    }
#pragma unroll
    for (int m = 32; m >= 1; m >>= 1) {
        s += __shfl_xor(s, m, 64);
        sq += __shfl_xor(sq, m, 64);
    }
    float mean = s * (1.f / 384.f);
    float var = sq * (1.f / 384.f) - mean * mean;
    float rstd = rsqrtf(var + 1e-5f);
    size_t orow = (size_t)row * 384;
#pragma unroll
    for (int i = 0; i < 6; i++) {
        int c = lane + i * 64;
        out[orow + c] = __float2bfloat16((v[i] - mean) * rstd * w[c] + b[c]);
    }
}

// ---- 128x384x(BK=64) bf16 MFMA GEMM, A[M,K] x Bt[N,K]^T, 1024 threads ------
// 16 waves as 4(M)x4(N); per-wave 32 rows x 96 cols (acc[2][6] f32x4).
// Per K-tile 64 KB staged: A 128x64 (16KB) + B 384x64 (48KB); thread t owns
// 4 16B-chunks: A chunk t (row t>>3, c t&7) and B chunks {t, 1024+t, 2048+t}
// (rows t>>3 +{0,128,256}, same c). Parity skeleton (round-4, verified):
//   iter T (parity P): ds_write staged regs (tile T+1) -> lb[P^1];
//   issue global loads (tile T+2); COMPUTE lb[P]; lgkmcnt(0); s_barrier.
//   No vmcnt drain in loop (compiler waits precisely on staged regs).
// LDS swizzle: row r stores logical chunk q at slot q^(r&7) (write-side
// applied directly; ds_read XORs with lm&7). 2-way bank access (free).
// EPI 0: +bias -> bf16 (qkv)        EPI 1: +bias, window-reverse+unshift,
// EPI 2: +bias, GELU -> bf16 (fc1)         +residual(x) -> f32 (proj)
// EPI 3: +bias +residual -> f32 (fc2)
template <int EPI>
__global__ __launch_bounds__(1024, 4) void gemm_k(
    const __hip_bfloat16* __restrict__ A, const __hip_bfloat16* __restrict__ Bt,
    const float* __restrict__ bias, int K, int nTilesN,
    __hip_bfloat16* outb, float* outf, const float* resin) {
    __shared__ __align__(16) __hip_bfloat16 lb[2][(128 + 384) * 64];  // 128 KiB
    // chunked XCD swizzle (all grids %8==0)
    int bid = blockIdx.x;
    bid = (bid & 7) * ((int)gridDim.x >> 3) + (bid >> 3);
    int tM = bid / nTilesN, tN = bid % nTilesN;
    size_t m0 = (size_t)tM * 128;
    int n0 = tN * 384;
    int tid = threadIdx.x, wv = tid >> 6, lane = tid & 63;
    int wr = wv >> 2, wc = wv & 3;  // wave grid 4(M) x 4(N)
    int lm = lane & 15, lg = lane >> 4;

    f32x4 acc[2][6];
#pragma unroll
    for (int m = 0; m < 2; m++)
#pragma unroll
        for (int j = 0; j < 6; j++) acc[m][j] = (f32x4){0.f, 0.f, 0.f, 0.f};

    // staging: thread t covers A chunk (row0,c0) + B chunks (row0+{0,128,256},c0)
    int row0 = tid >> 3, c0 = tid & 7;
    const __hip_bfloat16* gA = A + (m0 + row0) * K + c0 * 8;
    const __hip_bfloat16* gB = Bt + (size_t)(n0 + row0) * K + c0 * 8;
    int wofA = row0 * 64 + ((c0 ^ (row0 & 7)) * 8);  // swizzled write offset
    int wofB = 8192 + wofA;                          // B region; +8192/+16384 per l

    // ds_read swizzled chunk offsets (row&7 == lm&7 for all frag rows)
    int rsw0 = ((0 + lg) ^ (lm & 7)) * 8;
    int rsw1 = ((4 + lg) ^ (lm & 7)) * 8;
    int arow = (wr * 32 + lm) * 64;           // + m*1024
    int brow = 8192 + (wc * 96 + lm) * 64;    // + j*1024

    int nkt = K >> 6;  // 6 (K=384) or 24 (K=1536) -- always even

    bf16x8 st[4];  // staged regs: A, B+0, B+128, B+256

#define LOADT(T)                                                               \
    do {                                                                       \
        size_t k0_ = (size_t)(T) * 64;                                         \
        st[0] = *(const bf16x8*)(gA + k0_);                                    \
        st[1] = *(const bf16x8*)(gB + k0_);                                    \
        st[2] = *(const bf16x8*)(gB + (size_t)128 * K + k0_);                  \
        st[3] = *(const bf16x8*)(gB + (size_t)256 * K + k0_);                  \
    } while (0)
#define WRITET(P)                                                              \
    do {                                                                       \
        *(bf16x8*)&lb[P][wofA] = st[0];                                        \
        *(bf16x8*)&lb[P][wofB] = st[1];                                        \
        *(bf16x8*)&lb[P][wofB + 8192] = st[2];                                 \
        *(bf16x8*)&lb[P][wofB + 16384] = st[3];                                \
    } while (0)
#define COMPUTE(P)                                                             \
    do {                                                                       \
        bf16x8 af00 = *(const bf16x8*)&lb[P][arow + rsw0];                     \
        bf16x8 af01 = *(const bf16x8*)&lb[P][arow + rsw1];                     \
        bf16x8 af10 = *(const bf16x8*)&lb[P][arow + 1024 + rsw0];              \
        bf16x8 af11 = *(const bf16x8*)&lb[P][arow + 1024 + rsw1];              \
        _Pragma("unroll") for (int j = 0; j < 6; j++) {                        \
            bf16x8 b0 = *(const bf16x8*)&lb[P][brow + j * 1024 + rsw0];        \
            bf16x8 b1 = *(const bf16x8*)&lb[P][brow + j * 1024 + rsw1];        \
            acc[0][j] = __builtin_amdgcn_mfma_f32_16x16x32_bf16(               \
                af00, b0, acc[0][j], 0, 0, 0);                                 \
            acc[1][j] = __builtin_amdgcn_mfma_f32_16x16x32_bf16(               \
                af10, b0, acc[1][j], 0, 0, 0);                                 \
            acc[0][j] = __builtin_amdgcn_mfma_f32_16x16x32_bf16(               \
                af01, b1, acc[0][j], 0, 0, 0);                                 \
            acc[1][j] = __builtin_amdgcn_mfma_f32_16x16x32_bf16(               \
                af11, b1, acc[1][j], 0, 0, 0);                                 \
        }                                                                      \
    } while (0)
#define ENDBAR()                                                               \
    do {                                                                       \
        asm volatile("s_waitcnt lgkmcnt(0)" ::: "memory");                     \
        __builtin_amdgcn_sched_barrier(0);                                     \
        __builtin_amdgcn_s_barrier();                                          \
        __builtin_amdgcn_sched_barrier(0);                                     \
    } while (0)
#define ITER(P, T)                                                             \
    do {                                                                       \
        if ((T) + 1 < nkt) WRITET(P ^ 1);                                      \
        if ((T) + 2 < nkt) LOADT((T) + 2);                                     \
        COMPUTE(P);                                                            \
        ENDBAR();                                                              \
    } while (0)

    // prologue: tile 0 -> lb[0]; tile 1 staged in regs
    LOADT(0);
    WRITET(0);  // compiler inserts precise vmcnt wait for st
    LOADT(1);
    ENDBAR();

    for (int t = 0; t < nkt; t += 2) {
        ITER(0, t);
        ITER(1, t + 1);
    }
#undef ITER
#undef ENDBAR
#undef COMPUTE
#undef WRITET
#undef LOADT

    int ld = nTilesN * 384;
#pragma unroll
    for (int m = 0; m < 2; m++) {
#pragma unroll
        for (int r = 0; r < 4; r++) {
            int row = (int)m0 + wr * 32 + m * 16 + lg * 4 + r;
#pragma unroll
            for (int j = 0; j < 6; j++) {
                int col = n0 + wc * 96 + j * 16 + lm;
                float val = acc[m][j][r] + bias[col];
                if (EPI == 0) {
                    outb[(size_t)row * ld + col] = __float2bfloat16(val);
                } else if (EPI == 2) {
                    float g = 0.5f * val * (1.f + erff(val * 0.70710678118f));
                    outb[(size_t)row * ld + col] = __float2bfloat16(g);
                } else if (EPI == 1) {
                    // window-reverse + unshift + residual: row -> image pos
                    int wi = row / 49, t = row % 49;
                    int bb = wi >> 6, wrem = wi & 63;
                    int wh = wrem >> 3, ww = wrem & 7;
                    int th = t / 7, tw = t % 7;
                    int hi = (wh * 7 + th + 3) % 56;
                    int wimg = (ww * 7 + tw + 3) % 56;
                    size_t pos = (size_t)(bb * 3136 + hi * 56 + wimg) * 384 + col;
                    outf[pos] = resin[pos] + val;
                } else {  // EPI 3
                    size_t pos = (size_t)row * 384 + col;
                    outf[pos] = resin[pos] + val;
                }
            }
        }
    }
}

// ---- windowed attention: one block per (window, head) ----------------------
// LDS rows padded to 72 elems (144 B) -> 2-way bank access (free).
__global__ __launch_bounds__(256) void attn_k(const __hip_bfloat16* __restrict__ qkv,
                                              const float* __restrict__ biasM,
                                              __hip_bfloat16* __restrict__ out) {
    __shared__ __align__(16) __hip_bfloat16 vt[32 * 72];  // [dim][token(+pad)]
    __shared__ __align__(16) __hip_bfloat16 P[64 * 72];   // softmax probs
    // chunked XCD swizzle: 12 heads of a window share its qkv rows in L2
    int bid = blockIdx.x;
    bid = (bid & 7) * ((int)gridDim.x >> 3) + (bid >> 3);
    int wi = bid / 12, h = bid % 12;
    int tid = threadIdx.x, wv = tid >> 6, lane = tid & 63;
    int lm = lane & 15, lg = lane >> 4;
    int wrem = wi & 63, wh = wrem >> 3, ww = wrem & 7;

    // zero vt (covers token pad 49..71)
#pragma unroll
    for (int i = 0; i < 9; i++) vt[tid * 9 + i] = __float2bfloat16(0.f);
    __syncthreads();
    // stage v transposed: vt[d][t] = v[t][d]
    if (tid < 196) {
        int t = tid >> 2, d0 = (tid & 3) * 8;
        bf16x8 vv = *(const bf16x8*)(qkv + (size_t)(wi * 49 + t) * 1152 + 768 + h * 32 + d0);
#pragma unroll
        for (int i = 0; i < 8; i++) vt[(d0 + i) * 72 + t] = ((__hip_bfloat16*)&vv)[i];
    }

    // S = q @ k^T  (wave wv owns row-tile wv; frags straight from global)
    int qrow = wv * 16 + lm;
    if (qrow > 48) qrow = 48;
    bf16x8 aq = *(const bf16x8*)(qkv + (size_t)(wi * 49 + qrow) * 1152 + h * 32 + lg * 8);
    f32x4 S[4];
#pragma unroll
    for (int ct = 0; ct < 4; ct++) {
        int krow = ct * 16 + lm;
        if (krow > 48) krow = 48;
        bf16x8 bk = *(const bf16x8*)(qkv + (size_t)(wi * 49 + krow) * 1152 + 384 + h * 32 + lg * 8);
        S[ct] = __builtin_amdgcn_mfma_f32_16x16x32_bf16(aq, bk, (f32x4){0.f, 0.f, 0.f, 0.f}, 0, 0, 0);
    }

    // scale + rel-pos bias + shift mask + row softmax -> P (bf16, LDS)
    const float scale = 0.17677669529663687f;  // 32^-0.5
#pragma unroll
    for (int r = 0; r < 4; r++) {
        int irow = wv * 16 + lg * 4 + r;
        int ic = irow <= 48 ? irow : 48;
        int ith = ic / 7, itw = ic % 7;
        int ihs = wh * 7 + ith, iws = ww * 7 + itw;
        int ridi = (ihs < 49 ? 0 : (ihs < 53 ? 1 : 2)) * 3 + (iws < 49 ? 0 : (iws < 53 ? 1 : 2));
        float vals[4];
        float mx = -1e30f;
#pragma unroll
        for (int ct = 0; ct < 4; ct++) {
            int jcol = ct * 16 + lm;
            float sv;
            if (jcol < 49) {
                int jth = jcol / 7, jtw = jcol % 7;
                int jhs = wh * 7 + jth, jws = ww * 7 + jtw;
                int ridj = (jhs < 49 ? 0 : (jhs < 53 ? 1 : 2)) * 3 + (jws < 49 ? 0 : (jws < 53 ? 1 : 2));
                sv = S[ct][r] * scale + biasM[h * 2401 + ic * 49 + jcol] +
                     (ridi != ridj ? -100.f : 0.f);
            } else {
                sv = -1e30f;  // pad cols -> prob 0
            }
            vals[ct] = sv;
            mx = fmaxf(mx, sv);
        }
#pragma unroll
        for (int m = 8; m >= 1; m >>= 1) mx = fmaxf(mx, __shfl_xor(mx, m, 64));
        float sum = 0.f;
#pragma unroll
        for (int ct = 0; ct < 4; ct++) {
            vals[ct] = __expf(vals[ct] - mx);
            sum += vals[ct];
        }
#pragma unroll
        for (int m = 8; m >= 1; m >>= 1) sum += __shfl_xor(sum, m, 64);
        float inv = 1.f / sum;
#pragma unroll
        for (int ct = 0; ct < 4; ct++)
            P[irow * 72 + ct * 16 + lm] = __float2bfloat16(vals[ct] * inv);
    }
    __syncthreads();

    // O = P @ v   (K=64 = two 32-steps; N=32 = two col-tiles)
    f32x4 O[2] = {{0.f, 0.f, 0.f, 0.f}, {0.f, 0.f, 0.f, 0.f}};
#pragma unroll
    for (int ks = 0; ks < 2; ks++) {
        bf16x8 ap = *(const bf16x8*)&P[(wv * 16 + lm) * 72 + ks * 32 + lg * 8];
#pragma unroll
        for (int nt = 0; nt < 2; nt++) {
            bf16x8 bv = *(const bf16x8*)&vt[(nt * 16 + lm) * 72 + ks * 32 + lg * 8];
            O[nt] = __builtin_amdgcn_mfma_f32_16x16x32_bf16(ap, bv, O[nt], 0, 0, 0);
        }
    }
#pragma unroll
    for (int r = 0; r < 4; r++) {
        int row = wv * 16 + lg * 4 + r;
        if (row < 49) {
            size_t base = (size_t)(wi * 49 + row) * 384 + h * 32;
            out[base + lm] = __float2bfloat16(O[0][r]);
            out[base + 16 + lm] = __float2bfloat16(O[1][r]);
        }
    }
}

extern "C" void kernel_launch(void* const* d_in, const int* in_sizes, int n_in,
                              void* d_out, int out_size, void* d_ws, size_t ws_size,
                              hipStream_t stream) {
    (void)in_sizes; (void)n_in; (void)out_size; (void)ws_size;
    const float* x     = (const float*)d_in[0];
    const float* n1w   = (const float*)d_in[1];
    const float* n1b   = (const float*)d_in[2];
    const float* qkvw  = (const float*)d_in[3];
    const float* qkvb  = (const float*)d_in[4];
    const float* rpb   = (const float*)d_in[5];
    const float* projw = (const float*)d_in[6];
    const float* projb = (const float*)d_in[7];
    const float* n2w   = (const float*)d_in[8];
    const float* n2b   = (const float*)d_in[9];
    const float* fc1w  = (const float*)d_in[10];
    const float* fc1b  = (const float*)d_in[11];
    const float* fc2w  = (const float*)d_in[12];
    const float* fc2b  = (const float*)d_in[13];
    float* out = (float*)d_out;

    char* ws = (char*)d_ws;
    __hip_bfloat16* wt_qkv  = (__hip_bfloat16*)(ws + 0);
    __hip_bfloat16* wt_proj = (__hip_bfloat16*)(ws + 884736);
    __hip_bfloat16* wt_fc1  = (__hip_bfloat16*)(ws + 1179648);
    __hip_bfloat16* wt_fc2  = (__hip_bfloat16*)(ws + 2359296);
    float*          biasM   = (float*)(ws + 3538944);
    __hip_bfloat16* xw      = (__hip_bfloat16*)(ws + 3654656);
    __hip_bfloat16* qkv     = (__hip_bfloat16*)(ws + 80724992);
    __hip_bfloat16* attn_o  = (__hip_bfloat16*)(ws + 311936000);
    __hip_bfloat16* hidden  = xw;      // reuse xw+qkv region (308 MB)
    __hip_bfloat16* hn      = attn_o;  // reuse attn_out region

    // merged weight-convert + bias-matrix prep (1,798,284 elements)
    prep_k<<<7025, 256, 0, stream>>>(qkvw, projw, fc1w, fc2w, rpb,
                                     wt_qkv, wt_proj, wt_fc1, wt_fc2, biasM);

    // LN1 + cyclic shift + window partition
    ln_k<0><<<25088, 256, 0, stream>>>(x, n1w, n1b, xw);
    // QKV projection (grid 2352 % 8 == 0)
    gemm_k<0><<<784 * 3, 1024, 0, stream>>>(xw, wt_qkv, qkvb, 384, 3, qkv, nullptr, nullptr);
    // windowed attention (grid 24576 % 8 == 0)
    attn_k<<<2048 * 12, 256, 0, stream>>>(qkv, biasM, attn_o);
    // proj + window reverse + unshift + residual -> x_res (in d_out, fp32)
    gemm_k<1><<<784, 1024, 0, stream>>>(attn_o, wt_proj, projb, 384, 1, nullptr, out, x);
    // LN2
    ln_k<1><<<25088, 256, 0, stream>>>(out, n2w, n2b, hn);
    // fc1 + GELU (grid 3136 % 8 == 0)
    gemm_k<2><<<784 * 4, 1024, 0, stream>>>(hn, wt_fc1, fc1b, 384, 4, hidden, nullptr, nullptr);
    // fc2 + residual -> d_out
    gemm_k<3><<<784, 1024, 0, stream>>>(hidden, wt_fc2, fc2b, 1536, 1, nullptr, out, out);
}